// Round 10
// baseline (200.579 us; speedup 1.0000x reference)
//
#include <hip/hip_runtime.h>
#include <math.h>

#define M_SPATIAL 2097152  // 128^3
#define MV4 (M_SPATIAL / 4)

__device__ __forceinline__ float wave_redf(float v) {
#pragma unroll
  for (int o = 32; o > 0; o >>= 1) v += __shfl_down(v, o, 64);
  return v;
}
__device__ __forceinline__ double wave_redd(double v) {
#pragma unroll
  for (int o = 32; o > 0; o >>= 1) v += __shfl_down(v, o, 64);
  return v;
}
// Forced 3-input min (VOP3 v_min3_f32); exact, order-independent.
__device__ __forceinline__ float min3f(float a, float b, float c) {
  float d;
  asm("v_min3_f32 %0, %1, %2, %3" : "=v"(d) : "v"(a), "v"(b), "v"(c));
  return d;
}

// part layout (doubles):
// [0..511]=ce  [512..1023]=p  [1024..1535]=pt  [1536..2047]=t  (512 kAB blocks,
// blk<256 -> b=0)   [2048..2303]=dist (256 kCD blocks)
// g is stored TRANSPOSED: gT[b][yy][x][z]  (kAB writes coalesced; kCD staging
// reads 512B z-runs per yy row).

// ---------------------------------------------------------------------------
// kAB v2: LDS-staged X-EDT + fused CE/dice. Round-9 counters showed the old
// strided version at 51us, 660 GB/s: 48 scalar dword ops/thread at 64KB
// stride. Now: block = (b, yy, z-half) slab of 128x x 64z. Stage y+x with
// int4/float4 (256B runs), CE during staging; x-scan runs out of LDS
// (column reads 2-way = free, df in regs); h written back in-place; g out
// vec4-coalesced into the transposed layout.
// __launch_bounds__(256,2): VGPR cap 128, no spill (round-5 lesson).
// ---------------------------------------------------------------------------
__global__ __launch_bounds__(256, 2) void kAB(const int* __restrict__ y,
                                              const float* __restrict__ outputs,
                                              float* __restrict__ gT,
                                              double* __restrict__ part) {
  __shared__ int ysl[128 * 68];    // pitch 68 words (17 int4) -> aligned vec4
  __shared__ int lE[4][64];
  __shared__ int nE[4][64];
  __shared__ float sm[4][4];
  int blk = blockIdx.x;            // b*256 + yy*2 + zh
  int b  = blk >> 8;
  int yy = (blk >> 1) & 127;
  int zh = blk & 1;
  int t  = threadIdx.x;

  const int4*   y4  = (const int4*)y;
  const float4* xc4 = (const float4*)outputs + (size_t)(b * 2 + 1) * MV4;

  // ---- Stage slab (2048 int4) + CE/dice on the fly.
  float ce = 0.f, ps = 0.f, pts = 0.f, tsum = 0.f;
#pragma unroll
  for (int r = 0; r < 8; ++r) {
    int i4 = t + r * 256;          // 0..2047
    int x  = i4 >> 4;              // 0..127
    int u  = i4 & 15;              // int4 within 64-z run
    size_t sp4 = (size_t)x * 4096 + (size_t)yy * 32 + (size_t)zh * 16 + u;
    int4  yv = y4[(size_t)b * MV4 + sp4];
    float4 xv = xc4[sp4];
#define ELEM(cc, yc)                                                        \
    {                                                                       \
      float tt = (yc == 1) ? 1.0f : 0.0f;                                   \
      float xx = xv.cc;                                                     \
      ce += fmaxf(xx, 0.0f) - xx * tt + log1pf(expf(-fabsf(xx)));           \
      float p = 1.0f / (1.0f + expf(-xx));                                  \
      ps += p; pts += p * tt; tsum += tt;                                   \
    }
    ELEM(x, yv.x) ELEM(y, yv.y) ELEM(z, yv.z) ELEM(w, yv.w)
#undef ELEM
    *(int4*)&ysl[x * 68 + u * 4] = yv;
  }
  __syncthreads();

  // ---- X-EDT: thread owns column zl, chunk c of 32 x.
  int zl = t & 63, c = t >> 6;
  int x0 = c * 32;
  int yb[32];
#pragma unroll
  for (int k = 0; k < 32; ++k) yb[k] = ysl[(x0 + k) * 68 + zl];

  int lastE = -200, nextE = 400;
#pragma unroll
  for (int k = 0; k < 32; ++k) lastE = (yb[k] == 1) ? lastE : (x0 + k);
#pragma unroll
  for (int k = 31; k >= 0; --k) nextE = (yb[k] == 1) ? nextE : (x0 + k);
  lE[c][zl] = lastE;
  nE[c][zl] = nextE;
  __syncthreads();

  int carryL = -200, carryN = 400;
#pragma unroll
  for (int q = 0; q < 3; ++q) {
    if (q < c)     carryL = max(carryL, lE[q][zl]);
    if (q + 1 > c) carryN = min(carryN, nE[q + 1][zl]);
  }

  float yy2f = (float)(yy * yy);
  float hinf = 1000000.f + yy2f;

  int df[32];
  int ll = carryL;
#pragma unroll
  for (int k = 0; k < 32; ++k) {
    ll = (yb[k] == 1) ? ll : (x0 + k);
    df[k] = min(x0 + k - ll, 200);
  }
  float* hsl = (float*)ysl;        // reuse in place (own slots only)
  int nn = carryN;
#pragma unroll
  for (int k = 31; k >= 0; --k) {
    nn = (yb[k] == 1) ? nn : (x0 + k);
    int m = min(df[k], min(nn - (x0 + k), 200));
    hsl[(x0 + k) * 68 + zl] = (m >= 128) ? hinf : ((float)(m * m) + yy2f);
  }
  __syncthreads();                 // cross-thread: writeout reads all slots

  // ---- Coalesced writeout into transposed gT[b][yy][x][z].
  float4* gT4 = (float4*)gT;
#pragma unroll
  for (int r = 0; r < 8; ++r) {
    int i4 = t + r * 256;
    int x  = i4 >> 4;
    int u  = i4 & 15;
    float4 v = *(float4*)&hsl[x * 68 + u * 4];
    gT4[(size_t)b * MV4 + (size_t)yy * 4096 + (size_t)x * 32 +
        (size_t)zh * 16 + u] = v;
  }

  // ---- CE/dice partials.
  float r0 = wave_redf(ce), r1 = wave_redf(ps), r2 = wave_redf(pts), r3 = wave_redf(tsum);
  int lane = t & 63, w = t >> 6;
  if (lane == 0) { sm[w][0] = r0; sm[w][1] = r1; sm[w][2] = r2; sm[w][3] = r3; }
  __syncthreads();
  if (t == 0) {
    part[blk]        = (double)(sm[0][0] + sm[1][0] + sm[2][0] + sm[3][0]);
    part[512 + blk]  = (double)(sm[0][1] + sm[1][1] + sm[2][1] + sm[3][1]);
    part[1024 + blk] = (double)(sm[0][2] + sm[1][2] + sm[2][2] + sm[3][2]);
    part[1536 + blk] = (double)(sm[0][3] + sm[1][3] + sm[2][3] + sm[3][3]);
  }
}

// ---------------------------------------------------------------------------
// kCD: fused Y+Z windowed-exact EDT + dist loss, one block per (b,x) slab.
// Identical to round 9 except: staging reads the TRANSPOSED gT (512B z-runs
// per yy row) and the dist slot moved to part[2048+blk].
// ---------------------------------------------------------------------------
__global__ __launch_bounds__(512, 1) void kCD(const float* __restrict__ gT,
                                              const float* __restrict__ od,
                                              double* __restrict__ part) {
  __shared__ float hl[144 * 129];   // 74.3 KB
  __shared__ float sred[8];
  int blk = blockIdx.x;             // b*128 + xx
  int b = blk >> 7, xx = blk & 127;
  int t = threadIdx.x;

  // Pad rows (8 bottom, 8 top) with a value that can never win.
  for (int idx = t; idx < 8 * 129; idx += 512) {
    hl[idx] = 1.0e9f;
    hl[136 * 129 + idx] = 1.0e9f;
  }
  // Stage the slab from gT[b][yy][xx][z]: 4096 float4.
  const float4* gT4 = (const float4*)gT;
#pragma unroll
  for (int r = 0; r < 8; ++r) {
    int i4 = t + r * 512;           // 0..4095
    int yyi = i4 >> 5, u = i4 & 31; // u = z int4 (z4 = u*4)
    float4 v = gT4[(size_t)b * MV4 + (size_t)yyi * 4096 + (size_t)xx * 32 + u];
    float* p = &hl[(yyi + 8) * 129 + u * 4];
    p[0] = v.x; p[1] = v.y; p[2] = v.z; p[3] = v.w;
  }
  __syncthreads();

  // ---- Y pass: thread (z = t&127, ig = t>>7), 2 chunks x 16 y-outputs.
  int zcol = t & 127, ig = t >> 7;
  float dvy[2][16];
#pragma unroll
  for (int cb = 0; cb < 2; ++cb) {
    int ibase = ig * 32 + cb * 16;
    float best[16], mc[16];
#pragma unroll
    for (int k = 0; k < 16; ++k) {
      best[k] = 3.0e38f;
      mc[k] = -2.0f * (float)(ibase + k);
    }
    float jb = (float)(ibase - 8);
#pragma unroll 4
    for (int p = 0; p < 16; ++p) {     // rows [ibase, ibase+32) = yj+8
      float h0 = hl[(ibase + 2 * p) * 129 + zcol];
      float h1 = hl[(ibase + 2 * p + 1) * 129 + zcol];
      float j0 = jb + (float)(2 * p), j1 = jb + (float)(2 * p + 1);
#pragma unroll
      for (int k = 0; k < 16; ++k) {
        float v0 = fmaf(mc[k], j0, h0);
        float v1 = fmaf(mc[k], j1, h1);
        best[k] = min3f(v0, v1, best[k]);
      }
    }
    int ok = 1;
#pragma unroll
    for (int k = 0; k < 16; ++k) {
      int i = ibase + k;
      dvy[cb][k] = (float)(i * i) + best[k];
      float bnd = (float)min((k + 9) * (k + 9), (24 - k) * (24 - k));
      ok &= (dvy[cb][k] <= bnd);
    }
    if (!__all(ok)) {                   // exactness not certified -> full scan
#pragma unroll
      for (int k = 0; k < 16; ++k) best[k] = 3.0e38f;
#pragma unroll 2
      for (int j = 0; j < 128; j += 2) {
        float h0 = hl[(j + 8) * 129 + zcol];
        float h1 = hl[(j + 9) * 129 + zcol];
        float j0 = (float)j, j1 = (float)(j + 1);
#pragma unroll
        for (int k = 0; k < 16; ++k) {
          float v0 = fmaf(mc[k], j0, h0);
          float v1 = fmaf(mc[k], j1, h1);
          best[k] = min3f(v0, v1, best[k]);
        }
      }
#pragma unroll
      for (int k = 0; k < 16; ++k) {
        int i = ibase + k;
        dvy[cb][k] = (float)(i * i) + best[k];
      }
    }
  }
  __syncthreads();                      // ALL h reads complete
  // Transposed in-place write: hl[z+8][y] = dY^2 + z^2 (payload for Z pass).
  {
    float zq = (float)(zcol * zcol);
#pragma unroll
    for (int cb = 0; cb < 2; ++cb) {
      int ibase = ig * 32 + cb * 16;
#pragma unroll
      for (int k = 0; k < 16; ++k)
        hl[(zcol + 8) * 129 + (ibase + k)] = dvy[cb][k] + zq;
    }
  }
  __syncthreads();

  // ---- Z pass + dist: thread (y = t&127, izg = t>>7), 2 chunks x 16 z.
  int ycol = t & 127, izg = t >> 7;
  size_t odb = (size_t)(2 * b + 1) * M_SPATIAL + (size_t)xx * 16384 +
               (size_t)ycol * 128 + (size_t)izg * 32;
  const float4* o4 = (const float4*)(od + odb);
  float4 ovv[8];
#pragma unroll
  for (int r = 0; r < 8; ++r) ovv[r] = o4[r];
  const float* of = (const float*)ovv;

  float dist = 0.f;
#pragma unroll
  for (int cb = 0; cb < 2; ++cb) {
    int izb = izg * 32 + cb * 16;
    float best[16], mc[16];
#pragma unroll
    for (int k = 0; k < 16; ++k) {
      best[k] = 3.0e38f;
      mc[k] = -2.0f * (float)(izb + k);
    }
    float jb = (float)(izb - 8);
#pragma unroll 4
    for (int p = 0; p < 16; ++p) {     // rows [izb, izb+32) = zj+8
      float h0 = hl[(izb + 2 * p) * 129 + ycol];
      float h1 = hl[(izb + 2 * p + 1) * 129 + ycol];
      float j0 = jb + (float)(2 * p), j1 = jb + (float)(2 * p + 1);
#pragma unroll
      for (int k = 0; k < 16; ++k) {
        float v0 = fmaf(mc[k], j0, h0);
        float v1 = fmaf(mc[k], j1, h1);
        best[k] = min3f(v0, v1, best[k]);
      }
    }
    float dv[16];
    int ok = 1;
#pragma unroll
    for (int k = 0; k < 16; ++k) {
      int i = izb + k;
      dv[k] = (float)(i * i) + best[k];
      float bnd = (float)min((k + 9) * (k + 9), (24 - k) * (24 - k));
      ok &= (dv[k] <= bnd);
    }
    if (!__all(ok)) {
#pragma unroll
      for (int k = 0; k < 16; ++k) best[k] = 3.0e38f;
#pragma unroll 2
      for (int j = 0; j < 128; j += 2) {
        float h0 = hl[(j + 8) * 129 + ycol];
        float h1 = hl[(j + 9) * 129 + ycol];
        float j0 = (float)j, j1 = (float)(j + 1);
#pragma unroll
        for (int k = 0; k < 16; ++k) {
          float v0 = fmaf(mc[k], j0, h0);
          float v1 = fmaf(mc[k], j1, h1);
          best[k] = min3f(v0, v1, best[k]);
        }
      }
#pragma unroll
      for (int k = 0; k < 16; ++k) {
        int i = izb + k;
        dv[k] = (float)(i * i) + best[k];
      }
    }
#pragma unroll
    for (int k = 0; k < 16; ++k) {
      if (dv[k] > 0.f) dist += fabsf(of[cb * 16 + k] - sqrtf(dv[k]));
    }
  }
  float r = wave_redf(dist);
  int lane = t & 63, w = t >> 6;
  if (lane == 0) sred[w] = r;
  __syncthreads();
  if (t == 0) {
    float s = 0.f;
#pragma unroll
    for (int q = 0; q < 8; ++q) s += sred[q];
    part[2048 + blk] = (double)s;
  }
}

// ---------------------------------------------------------------------------
// k_final: reduce partials (512 ce/dice slots, 256 dist slots) -> loss.
// kAB blocks 0..255 are b=0, 256..511 are b=1 -> per-batch slices align with
// thread index directly.
// ---------------------------------------------------------------------------
__global__ __launch_bounds__(256) void k_final(const double* __restrict__ part,
                                               const float* __restrict__ wptr,
                                               float* __restrict__ out) {
  int i = threadIdx.x;
  double ce  = part[i] + part[i + 256];
  double p0  = part[512 + i];
  double p1  = part[768 + i];
  double pt0 = part[1024 + i];
  double pt1 = part[1280 + i];
  double t0  = part[1536 + i];
  double t1  = part[1792 + i];
  double ds  = part[2048 + i];   // 256 kCD blocks

  ce = wave_redd(ce); p0 = wave_redd(p0); p1 = wave_redd(p1);
  pt0 = wave_redd(pt0); pt1 = wave_redd(pt1);
  t0 = wave_redd(t0); t1 = wave_redd(t1); ds = wave_redd(ds);

  __shared__ double sm[4][8];
  int lane = threadIdx.x & 63, w = threadIdx.x >> 6;
  if (lane == 0) {
    sm[w][0] = ce; sm[w][1] = p0; sm[w][2] = p1; sm[w][3] = pt0;
    sm[w][4] = pt1; sm[w][5] = t0; sm[w][6] = t1; sm[w][7] = ds;
  }
  __syncthreads();
  if (threadIdx.x == 0) {
    double a[8];
    for (int q = 0; q < 8; ++q) a[q] = sm[0][q] + sm[1][q] + sm[2][q] + sm[3][q];
    double cem = a[0] / 4194304.0;
    double dice0 = (2.0 * a[3] + 1.0) / (a[1] + a[5] + 1.0);
    double dice1 = (2.0 * a[4] + 1.0) / (a[2] + a[6] + 1.0);
    double ldice = 1.0 - 0.5 * (dice0 + dice1);
    double msum = a[5] + a[6];
    double ldist = (msum == 0.0) ? 0.0 : a[7] / fmax(msum, 1e-12);
    out[0] = (float)(cem + ldice + (double)wptr[0] * ldist);
  }
}

extern "C" void kernel_launch(void* const* d_in, const int* in_sizes, int n_in,
                              void* d_out, int out_size, void* d_ws, size_t ws_size,
                              hipStream_t stream) {
  const float* outputs      = (const float*)d_in[0];
  const float* outputs_dist = (const float*)d_in[1];
  const int*   y            = (const int*)d_in[2];
  const float* wptr         = (const float*)d_in[3];
  float* out = (float*)d_out;

  double* part = (double*)d_ws;                    // 2304 doubles
  float* gT = (float*)((char*)d_ws + 65536);       // 16 MiB transposed h field

  kAB<<<512, 256, 0, stream>>>(y, outputs, gT, part);      // X + CE/dice
  kCD<<<256, 512, 0, stream>>>(gT, outputs_dist, part);    // fused Y+Z + dist
  k_final<<<1, 256, 0, stream>>>(part, wptr, out);
}

// Round 11
// 160.134 us; speedup vs baseline: 1.2526x; 1.2526x over previous
//
#include <hip/hip_runtime.h>
#include <math.h>

#define M_SPATIAL 2097152  // 128^3
#define MV4 (M_SPATIAL / 4)

__device__ __forceinline__ float wave_redf(float v) {
#pragma unroll
  for (int o = 32; o > 0; o >>= 1) v += __shfl_down(v, o, 64);
  return v;
}
__device__ __forceinline__ double wave_redd(double v) {
#pragma unroll
  for (int o = 32; o > 0; o >>= 1) v += __shfl_down(v, o, 64);
  return v;
}
// Forced 3-input min (VOP3 v_min3_f32); exact, order-independent.
__device__ __forceinline__ float min3f(float a, float b, float c) {
  float d;
  asm("v_min3_f32 %0, %1, %2, %3" : "=v"(d) : "v"(a), "v"(b), "v"(c));
  return d;
}

// part layout (doubles):
// [0..511]=ce  [512..1023]=p  [1024..1535]=pt  [1536..2047]=t  (512 kAB blocks,
// blk<256 -> b=0)   [2048..2303]=dist (256 kCD blocks)
// g is stored TRANSPOSED: gT[b][yy][x][z].

// ---------------------------------------------------------------------------
// kAB v3: LDS-staged X-EDT + fused CE/dice, scan run THROUGH LDS.
// Round-10 failure: yb[32]+df[32] register arrays + 128-VGPR cap -> scratch
// spills (WRITE 150MB). v3 keeps zero big register arrays: three in-place
// passes over the thread's own column slots (y -> df -> h), only scalar
// carries live in registers. Staging + transposed-gT writeout unchanged
// (validated by round 10: kCD consumed gT correctly, absmax 0).
// ---------------------------------------------------------------------------
__global__ __launch_bounds__(256) void kAB(const int* __restrict__ y,
                                           const float* __restrict__ outputs,
                                           float* __restrict__ gT,
                                           double* __restrict__ part) {
  __shared__ int ysl[128 * 68];    // pitch 68 words (17 int4) -> aligned vec4
  __shared__ int lE[4][64];
  __shared__ int nE[4][64];
  __shared__ float sm[4][4];
  int blk = blockIdx.x;            // b*256 + yy*2 + zh
  int b  = blk >> 8;
  int yy = (blk >> 1) & 127;
  int zh = blk & 1;
  int t  = threadIdx.x;

  const int4*   y4  = (const int4*)y;
  const float4* xc4 = (const float4*)outputs + (size_t)(b * 2 + 1) * MV4;

  // ---- Stage slab (2048 int4) + CE/dice on the fly.
  float ce = 0.f, ps = 0.f, pts = 0.f, tsum = 0.f;
#pragma unroll
  for (int r = 0; r < 8; ++r) {
    int i4 = t + r * 256;          // 0..2047
    int x  = i4 >> 4;              // 0..127
    int u  = i4 & 15;              // int4 within 64-z run
    size_t sp4 = (size_t)x * 4096 + (size_t)yy * 32 + (size_t)zh * 16 + u;
    int4  yv = y4[(size_t)b * MV4 + sp4];
    float4 xv = xc4[sp4];
#define ELEM(cc, yc)                                                        \
    {                                                                       \
      float tt = (yc == 1) ? 1.0f : 0.0f;                                   \
      float xx = xv.cc;                                                     \
      ce += fmaxf(xx, 0.0f) - xx * tt + log1pf(expf(-fabsf(xx)));           \
      float p = 1.0f / (1.0f + expf(-xx));                                  \
      ps += p; pts += p * tt; tsum += tt;                                   \
    }
    ELEM(x, yv.x) ELEM(y, yv.y) ELEM(z, yv.z) ELEM(w, yv.w)
#undef ELEM
    *(int4*)&ysl[x * 68 + u * 4] = yv;
  }
  __syncthreads();

  // ---- X-EDT through LDS: thread owns column zl, chunk c of 32 x.
  int zl = t & 63, c = t >> 6;
  int x0 = c * 32;

  // Pass A: chunk summaries (no arrays kept).
  int lastE = -200, nextE = 400;
#pragma unroll
  for (int k = 0; k < 32; ++k) {
    int fg = ysl[(x0 + k) * 68 + zl];
    lastE = (fg == 1) ? lastE : (x0 + k);
    nextE = (fg == 1) ? nextE : min(nextE, x0 + k);
  }
  lE[c][zl] = lastE;
  nE[c][zl] = nextE;
  __syncthreads();

  int carryL = -200, carryN = 400;
#pragma unroll
  for (int q = 0; q < 3; ++q) {
    if (q < c)     carryL = max(carryL, lE[q][zl]);
    if (q + 1 > c) carryN = min(carryN, nE[q + 1][zl]);
  }

  float yy2f = (float)(yy * yy);
  float hinf = 1000000.f + yy2f;

  // Pass B: forward chain, overwrite y slot with df (slot consumed at k).
  int ll = carryL;
#pragma unroll
  for (int k = 0; k < 32; ++k) {
    int idx = (x0 + k) * 68 + zl;
    int fg = ysl[idx];
    ll = (fg == 1) ? ll : (x0 + k);
    ysl[idx] = min(x0 + k - ll, 200);     // df (0 iff bg)
  }
  // Pass C: backward chain, overwrite df slot with final h (float).
  float* hsl = (float*)ysl;
  int nn = carryN;
#pragma unroll
  for (int k = 31; k >= 0; --k) {
    int idx = (x0 + k) * 68 + zl;
    int dfk = ysl[idx];
    nn = (dfk > 0) ? nn : (x0 + k);       // df==0 iff bg
    int m = min(dfk, min(nn - (x0 + k), 200));
    hsl[idx] = (m >= 128) ? hinf : ((float)(m * m) + yy2f);
  }
  __syncthreads();                 // cross-thread: writeout reads all slots

  // ---- Coalesced writeout into transposed gT[b][yy][x][z].
  float4* gT4 = (float4*)gT;
#pragma unroll
  for (int r = 0; r < 8; ++r) {
    int i4 = t + r * 256;
    int x  = i4 >> 4;
    int u  = i4 & 15;
    float4 v = *(float4*)&hsl[x * 68 + u * 4];
    gT4[(size_t)b * MV4 + (size_t)yy * 4096 + (size_t)x * 32 +
        (size_t)zh * 16 + u] = v;
  }

  // ---- CE/dice partials.
  float r0 = wave_redf(ce), r1 = wave_redf(ps), r2 = wave_redf(pts), r3 = wave_redf(tsum);
  int lane = t & 63, w = t >> 6;
  if (lane == 0) { sm[w][0] = r0; sm[w][1] = r1; sm[w][2] = r2; sm[w][3] = r3; }
  __syncthreads();
  if (t == 0) {
    part[blk]        = (double)(sm[0][0] + sm[1][0] + sm[2][0] + sm[3][0]);
    part[512 + blk]  = (double)(sm[0][1] + sm[1][1] + sm[2][1] + sm[3][1]);
    part[1024 + blk] = (double)(sm[0][2] + sm[1][2] + sm[2][2] + sm[3][2]);
    part[1536 + blk] = (double)(sm[0][3] + sm[1][3] + sm[2][3] + sm[3][3]);
  }
}

// ---------------------------------------------------------------------------
// kCD: fused Y+Z windowed-exact EDT + dist loss, one block per (b,x) slab.
// Unchanged from round 10 (validated: below profiling cutoff, absmax 0).
// ---------------------------------------------------------------------------
__global__ __launch_bounds__(512, 1) void kCD(const float* __restrict__ gT,
                                              const float* __restrict__ od,
                                              double* __restrict__ part) {
  __shared__ float hl[144 * 129];   // 74.3 KB
  __shared__ float sred[8];
  int blk = blockIdx.x;             // b*128 + xx
  int b = blk >> 7, xx = blk & 127;
  int t = threadIdx.x;

  for (int idx = t; idx < 8 * 129; idx += 512) {
    hl[idx] = 1.0e9f;
    hl[136 * 129 + idx] = 1.0e9f;
  }
  const float4* gT4 = (const float4*)gT;
#pragma unroll
  for (int r = 0; r < 8; ++r) {
    int i4 = t + r * 512;           // 0..4095
    int yyi = i4 >> 5, u = i4 & 31;
    float4 v = gT4[(size_t)b * MV4 + (size_t)yyi * 4096 + (size_t)xx * 32 + u];
    float* p = &hl[(yyi + 8) * 129 + u * 4];
    p[0] = v.x; p[1] = v.y; p[2] = v.z; p[3] = v.w;
  }
  __syncthreads();

  // ---- Y pass: thread (z = t&127, ig = t>>7), 2 chunks x 16 y-outputs.
  int zcol = t & 127, ig = t >> 7;
  float dvy[2][16];
#pragma unroll
  for (int cb = 0; cb < 2; ++cb) {
    int ibase = ig * 32 + cb * 16;
    float best[16], mc[16];
#pragma unroll
    for (int k = 0; k < 16; ++k) {
      best[k] = 3.0e38f;
      mc[k] = -2.0f * (float)(ibase + k);
    }
    float jb = (float)(ibase - 8);
#pragma unroll 4
    for (int p = 0; p < 16; ++p) {
      float h0 = hl[(ibase + 2 * p) * 129 + zcol];
      float h1 = hl[(ibase + 2 * p + 1) * 129 + zcol];
      float j0 = jb + (float)(2 * p), j1 = jb + (float)(2 * p + 1);
#pragma unroll
      for (int k = 0; k < 16; ++k) {
        float v0 = fmaf(mc[k], j0, h0);
        float v1 = fmaf(mc[k], j1, h1);
        best[k] = min3f(v0, v1, best[k]);
      }
    }
    int ok = 1;
#pragma unroll
    for (int k = 0; k < 16; ++k) {
      int i = ibase + k;
      dvy[cb][k] = (float)(i * i) + best[k];
      float bnd = (float)min((k + 9) * (k + 9), (24 - k) * (24 - k));
      ok &= (dvy[cb][k] <= bnd);
    }
    if (!__all(ok)) {
#pragma unroll
      for (int k = 0; k < 16; ++k) best[k] = 3.0e38f;
#pragma unroll 2
      for (int j = 0; j < 128; j += 2) {
        float h0 = hl[(j + 8) * 129 + zcol];
        float h1 = hl[(j + 9) * 129 + zcol];
        float j0 = (float)j, j1 = (float)(j + 1);
#pragma unroll
        for (int k = 0; k < 16; ++k) {
          float v0 = fmaf(mc[k], j0, h0);
          float v1 = fmaf(mc[k], j1, h1);
          best[k] = min3f(v0, v1, best[k]);
        }
      }
#pragma unroll
      for (int k = 0; k < 16; ++k) {
        int i = ibase + k;
        dvy[cb][k] = (float)(i * i) + best[k];
      }
    }
  }
  __syncthreads();
  {
    float zq = (float)(zcol * zcol);
#pragma unroll
    for (int cb = 0; cb < 2; ++cb) {
      int ibase = ig * 32 + cb * 16;
#pragma unroll
      for (int k = 0; k < 16; ++k)
        hl[(zcol + 8) * 129 + (ibase + k)] = dvy[cb][k] + zq;
    }
  }
  __syncthreads();

  // ---- Z pass + dist: thread (y = t&127, izg = t>>7), 2 chunks x 16 z.
  int ycol = t & 127, izg = t >> 7;
  size_t odb = (size_t)(2 * b + 1) * M_SPATIAL + (size_t)xx * 16384 +
               (size_t)ycol * 128 + (size_t)izg * 32;
  const float4* o4 = (const float4*)(od + odb);
  float4 ovv[8];
#pragma unroll
  for (int r = 0; r < 8; ++r) ovv[r] = o4[r];
  const float* of = (const float*)ovv;

  float dist = 0.f;
#pragma unroll
  for (int cb = 0; cb < 2; ++cb) {
    int izb = izg * 32 + cb * 16;
    float best[16], mc[16];
#pragma unroll
    for (int k = 0; k < 16; ++k) {
      best[k] = 3.0e38f;
      mc[k] = -2.0f * (float)(izb + k);
    }
    float jb = (float)(izb - 8);
#pragma unroll 4
    for (int p = 0; p < 16; ++p) {
      float h0 = hl[(izb + 2 * p) * 129 + ycol];
      float h1 = hl[(izb + 2 * p + 1) * 129 + ycol];
      float j0 = jb + (float)(2 * p), j1 = jb + (float)(2 * p + 1);
#pragma unroll
      for (int k = 0; k < 16; ++k) {
        float v0 = fmaf(mc[k], j0, h0);
        float v1 = fmaf(mc[k], j1, h1);
        best[k] = min3f(v0, v1, best[k]);
      }
    }
    float dv[16];
    int ok = 1;
#pragma unroll
    for (int k = 0; k < 16; ++k) {
      int i = izb + k;
      dv[k] = (float)(i * i) + best[k];
      float bnd = (float)min((k + 9) * (k + 9), (24 - k) * (24 - k));
      ok &= (dv[k] <= bnd);
    }
    if (!__all(ok)) {
#pragma unroll
      for (int k = 0; k < 16; ++k) best[k] = 3.0e38f;
#pragma unroll 2
      for (int j = 0; j < 128; j += 2) {
        float h0 = hl[(j + 8) * 129 + ycol];
        float h1 = hl[(j + 9) * 129 + ycol];
        float j0 = (float)j, j1 = (float)(j + 1);
#pragma unroll
        for (int k = 0; k < 16; ++k) {
          float v0 = fmaf(mc[k], j0, h0);
          float v1 = fmaf(mc[k], j1, h1);
          best[k] = min3f(v0, v1, best[k]);
        }
      }
#pragma unroll
      for (int k = 0; k < 16; ++k) {
        int i = izb + k;
        dv[k] = (float)(i * i) + best[k];
      }
    }
#pragma unroll
    for (int k = 0; k < 16; ++k) {
      if (dv[k] > 0.f) dist += fabsf(of[cb * 16 + k] - sqrtf(dv[k]));
    }
  }
  float r = wave_redf(dist);
  int lane = t & 63, w = t >> 6;
  if (lane == 0) sred[w] = r;
  __syncthreads();
  if (t == 0) {
    float s = 0.f;
#pragma unroll
    for (int q = 0; q < 8; ++q) s += sred[q];
    part[2048 + blk] = (double)s;
  }
}

// ---------------------------------------------------------------------------
// k_final: reduce partials (512 ce/dice slots, 256 dist slots) -> loss.
// ---------------------------------------------------------------------------
__global__ __launch_bounds__(256) void k_final(const double* __restrict__ part,
                                               const float* __restrict__ wptr,
                                               float* __restrict__ out) {
  int i = threadIdx.x;
  double ce  = part[i] + part[i + 256];
  double p0  = part[512 + i];
  double p1  = part[768 + i];
  double pt0 = part[1024 + i];
  double pt1 = part[1280 + i];
  double t0  = part[1536 + i];
  double t1  = part[1792 + i];
  double ds  = part[2048 + i];   // 256 kCD blocks

  ce = wave_redd(ce); p0 = wave_redd(p0); p1 = wave_redd(p1);
  pt0 = wave_redd(pt0); pt1 = wave_redd(pt1);
  t0 = wave_redd(t0); t1 = wave_redd(t1); ds = wave_redd(ds);

  __shared__ double sm[4][8];
  int lane = threadIdx.x & 63, w = threadIdx.x >> 6;
  if (lane == 0) {
    sm[w][0] = ce; sm[w][1] = p0; sm[w][2] = p1; sm[w][3] = pt0;
    sm[w][4] = pt1; sm[w][5] = t0; sm[w][6] = t1; sm[w][7] = ds;
  }
  __syncthreads();
  if (threadIdx.x == 0) {
    double a[8];
    for (int q = 0; q < 8; ++q) a[q] = sm[0][q] + sm[1][q] + sm[2][q] + sm[3][q];
    double cem = a[0] / 4194304.0;
    double dice0 = (2.0 * a[3] + 1.0) / (a[1] + a[5] + 1.0);
    double dice1 = (2.0 * a[4] + 1.0) / (a[2] + a[6] + 1.0);
    double ldice = 1.0 - 0.5 * (dice0 + dice1);
    double msum = a[5] + a[6];
    double ldist = (msum == 0.0) ? 0.0 : a[7] / fmax(msum, 1e-12);
    out[0] = (float)(cem + ldice + (double)wptr[0] * ldist);
  }
}

extern "C" void kernel_launch(void* const* d_in, const int* in_sizes, int n_in,
                              void* d_out, int out_size, void* d_ws, size_t ws_size,
                              hipStream_t stream) {
  const float* outputs      = (const float*)d_in[0];
  const float* outputs_dist = (const float*)d_in[1];
  const int*   y            = (const int*)d_in[2];
  const float* wptr         = (const float*)d_in[3];
  float* out = (float*)d_out;

  double* part = (double*)d_ws;                    // 2304 doubles
  float* gT = (float*)((char*)d_ws + 65536);       // 16 MiB transposed h field

  kAB<<<512, 256, 0, stream>>>(y, outputs, gT, part);      // X + CE/dice
  kCD<<<256, 512, 0, stream>>>(gT, outputs_dist, part);    // fused Y+Z + dist
  k_final<<<1, 256, 0, stream>>>(part, wptr, out);
}

// Round 12
// 153.377 us; speedup vs baseline: 1.3077x; 1.0441x over previous
//
#include <hip/hip_runtime.h>
#include <math.h>

#define M_SPATIAL 2097152  // 128^3
#define MV4 (M_SPATIAL / 4)

__device__ __forceinline__ float wave_redf(float v) {
#pragma unroll
  for (int o = 32; o > 0; o >>= 1) v += __shfl_down(v, o, 64);
  return v;
}
__device__ __forceinline__ double wave_redd(double v) {
#pragma unroll
  for (int o = 32; o > 0; o >>= 1) v += __shfl_down(v, o, 64);
  return v;
}
// Forced 3-input min (VOP3 v_min3_f32); exact, order-independent.
__device__ __forceinline__ float min3f(float a, float b, float c) {
  float d;
  asm("v_min3_f32 %0, %1, %2, %3" : "=v"(d) : "v"(a), "v"(b), "v"(c));
  return d;
}

// part layout (doubles):
// [0..511]=ce  [512..1023]=p  [1024..1535]=pt  [1536..2047]=t  (512 kAB blocks,
// blk<256 -> b=0)   [2048..2303]=dist (256 kCD blocks)
// g is stored TRANSPOSED: gT[b][yy][x][z].

// ---------------------------------------------------------------------------
// kAB v4 = round-10 v2 (register-array scan, LDS-staged slab, transposed gT
// writeout — VERIFIED CORRECT in r10) with the register budget fixed:
// __launch_bounds__(256, 1) lifts the VGPR cap to 256+, so yb[32]+df[32]
// (~150 live regs) fit WITHOUT scratch spill. r10's 150MB scratch WRITE came
// solely from the (256,2) cap of 128; r11's LDS-RMW variant backfired (244
// VGPR, LDS latency chains). This is the only untested—and principled—cell.
// ---------------------------------------------------------------------------
__global__ __launch_bounds__(256, 1) void kAB(const int* __restrict__ y,
                                              const float* __restrict__ outputs,
                                              float* __restrict__ gT,
                                              double* __restrict__ part) {
  __shared__ int ysl[128 * 68];    // pitch 68 words (17 int4) -> aligned vec4
  __shared__ int lE[4][64];
  __shared__ int nE[4][64];
  __shared__ float sm[4][4];
  int blk = blockIdx.x;            // b*256 + yy*2 + zh
  int b  = blk >> 8;
  int yy = (blk >> 1) & 127;
  int zh = blk & 1;
  int t  = threadIdx.x;

  const int4*   y4  = (const int4*)y;
  const float4* xc4 = (const float4*)outputs + (size_t)(b * 2 + 1) * MV4;

  // ---- Stage slab (2048 int4) + CE/dice on the fly.
  float ce = 0.f, ps = 0.f, pts = 0.f, tsum = 0.f;
#pragma unroll
  for (int r = 0; r < 8; ++r) {
    int i4 = t + r * 256;          // 0..2047
    int x  = i4 >> 4;              // 0..127
    int u  = i4 & 15;              // int4 within 64-z run
    size_t sp4 = (size_t)x * 4096 + (size_t)yy * 32 + (size_t)zh * 16 + u;
    int4  yv = y4[(size_t)b * MV4 + sp4];
    float4 xv = xc4[sp4];
#define ELEM(cc, yc)                                                        \
    {                                                                       \
      float tt = (yc == 1) ? 1.0f : 0.0f;                                   \
      float xx = xv.cc;                                                     \
      ce += fmaxf(xx, 0.0f) - xx * tt + log1pf(expf(-fabsf(xx)));           \
      float p = 1.0f / (1.0f + expf(-xx));                                  \
      ps += p; pts += p * tt; tsum += tt;                                   \
    }
    ELEM(x, yv.x) ELEM(y, yv.y) ELEM(z, yv.z) ELEM(w, yv.w)
#undef ELEM
    *(int4*)&ysl[x * 68 + u * 4] = yv;
  }
  __syncthreads();

  // ---- X-EDT: thread owns column zl (64 z), chunk c of 32 x.
  int zl = t & 63, c = t >> 6;
  int x0 = c * 32;
  int yb[32];
#pragma unroll
  for (int k = 0; k < 32; ++k) yb[k] = ysl[(x0 + k) * 68 + zl];

  int lastE = -200, nextE = 400;
#pragma unroll
  for (int k = 0; k < 32; ++k) lastE = (yb[k] == 1) ? lastE : (x0 + k);
#pragma unroll
  for (int k = 31; k >= 0; --k) nextE = (yb[k] == 1) ? nextE : (x0 + k);
  lE[c][zl] = lastE;
  nE[c][zl] = nextE;
  __syncthreads();

  int carryL = -200, carryN = 400;
#pragma unroll
  for (int q = 0; q < 3; ++q) {
    if (q < c)     carryL = max(carryL, lE[q][zl]);
    if (q + 1 > c) carryN = min(carryN, nE[q + 1][zl]);
  }

  float yy2f = (float)(yy * yy);
  float hinf = 1000000.f + yy2f;

  int df[32];
  int ll = carryL;
#pragma unroll
  for (int k = 0; k < 32; ++k) {
    ll = (yb[k] == 1) ? ll : (x0 + k);
    df[k] = min(x0 + k - ll, 200);
  }
  float* hsl = (float*)ysl;        // reuse in place (own slots only)
  int nn = carryN;
#pragma unroll
  for (int k = 31; k >= 0; --k) {
    nn = (yb[k] == 1) ? nn : (x0 + k);
    int m = min(df[k], min(nn - (x0 + k), 200));
    hsl[(x0 + k) * 68 + zl] = (m >= 128) ? hinf : ((float)(m * m) + yy2f);
  }
  __syncthreads();                 // cross-thread: writeout reads all slots

  // ---- Coalesced writeout into transposed gT[b][yy][x][z].
  float4* gT4 = (float4*)gT;
#pragma unroll
  for (int r = 0; r < 8; ++r) {
    int i4 = t + r * 256;
    int x  = i4 >> 4;
    int u  = i4 & 15;
    float4 v = *(float4*)&hsl[x * 68 + u * 4];
    gT4[(size_t)b * MV4 + (size_t)yy * 4096 + (size_t)x * 32 +
        (size_t)zh * 16 + u] = v;
  }

  // ---- CE/dice partials.
  float r0 = wave_redf(ce), r1 = wave_redf(ps), r2 = wave_redf(pts), r3 = wave_redf(tsum);
  int lane = t & 63, w = t >> 6;
  if (lane == 0) { sm[w][0] = r0; sm[w][1] = r1; sm[w][2] = r2; sm[w][3] = r3; }
  __syncthreads();
  if (t == 0) {
    part[blk]        = (double)(sm[0][0] + sm[1][0] + sm[2][0] + sm[3][0]);
    part[512 + blk]  = (double)(sm[0][1] + sm[1][1] + sm[2][1] + sm[3][1]);
    part[1024 + blk] = (double)(sm[0][2] + sm[1][2] + sm[2][2] + sm[3][2]);
    part[1536 + blk] = (double)(sm[0][3] + sm[1][3] + sm[2][3] + sm[3][3]);
  }
}

// ---------------------------------------------------------------------------
// kCD: fused Y+Z windowed-exact EDT + dist loss, one block per (b,x) slab.
// Unchanged from rounds 10/11 (validated: below profiling cutoff, absmax 0).
// ---------------------------------------------------------------------------
__global__ __launch_bounds__(512, 1) void kCD(const float* __restrict__ gT,
                                              const float* __restrict__ od,
                                              double* __restrict__ part) {
  __shared__ float hl[144 * 129];   // 74.3 KB
  __shared__ float sred[8];
  int blk = blockIdx.x;             // b*128 + xx
  int b = blk >> 7, xx = blk & 127;
  int t = threadIdx.x;

  for (int idx = t; idx < 8 * 129; idx += 512) {
    hl[idx] = 1.0e9f;
    hl[136 * 129 + idx] = 1.0e9f;
  }
  const float4* gT4 = (const float4*)gT;
#pragma unroll
  for (int r = 0; r < 8; ++r) {
    int i4 = t + r * 512;           // 0..4095
    int yyi = i4 >> 5, u = i4 & 31;
    float4 v = gT4[(size_t)b * MV4 + (size_t)yyi * 4096 + (size_t)xx * 32 + u];
    float* p = &hl[(yyi + 8) * 129 + u * 4];
    p[0] = v.x; p[1] = v.y; p[2] = v.z; p[3] = v.w;
  }
  __syncthreads();

  // ---- Y pass: thread (z = t&127, ig = t>>7), 2 chunks x 16 y-outputs.
  int zcol = t & 127, ig = t >> 7;
  float dvy[2][16];
#pragma unroll
  for (int cb = 0; cb < 2; ++cb) {
    int ibase = ig * 32 + cb * 16;
    float best[16], mc[16];
#pragma unroll
    for (int k = 0; k < 16; ++k) {
      best[k] = 3.0e38f;
      mc[k] = -2.0f * (float)(ibase + k);
    }
    float jb = (float)(ibase - 8);
#pragma unroll 4
    for (int p = 0; p < 16; ++p) {
      float h0 = hl[(ibase + 2 * p) * 129 + zcol];
      float h1 = hl[(ibase + 2 * p + 1) * 129 + zcol];
      float j0 = jb + (float)(2 * p), j1 = jb + (float)(2 * p + 1);
#pragma unroll
      for (int k = 0; k < 16; ++k) {
        float v0 = fmaf(mc[k], j0, h0);
        float v1 = fmaf(mc[k], j1, h1);
        best[k] = min3f(v0, v1, best[k]);
      }
    }
    int ok = 1;
#pragma unroll
    for (int k = 0; k < 16; ++k) {
      int i = ibase + k;
      dvy[cb][k] = (float)(i * i) + best[k];
      float bnd = (float)min((k + 9) * (k + 9), (24 - k) * (24 - k));
      ok &= (dvy[cb][k] <= bnd);
    }
    if (!__all(ok)) {
#pragma unroll
      for (int k = 0; k < 16; ++k) best[k] = 3.0e38f;
#pragma unroll 2
      for (int j = 0; j < 128; j += 2) {
        float h0 = hl[(j + 8) * 129 + zcol];
        float h1 = hl[(j + 9) * 129 + zcol];
        float j0 = (float)j, j1 = (float)(j + 1);
#pragma unroll
        for (int k = 0; k < 16; ++k) {
          float v0 = fmaf(mc[k], j0, h0);
          float v1 = fmaf(mc[k], j1, h1);
          best[k] = min3f(v0, v1, best[k]);
        }
      }
#pragma unroll
      for (int k = 0; k < 16; ++k) {
        int i = ibase + k;
        dvy[cb][k] = (float)(i * i) + best[k];
      }
    }
  }
  __syncthreads();
  {
    float zq = (float)(zcol * zcol);
#pragma unroll
    for (int cb = 0; cb < 2; ++cb) {
      int ibase = ig * 32 + cb * 16;
#pragma unroll
      for (int k = 0; k < 16; ++k)
        hl[(zcol + 8) * 129 + (ibase + k)] = dvy[cb][k] + zq;
    }
  }
  __syncthreads();

  // ---- Z pass + dist: thread (y = t&127, izg = t>>7), 2 chunks x 16 z.
  int ycol = t & 127, izg = t >> 7;
  size_t odb = (size_t)(2 * b + 1) * M_SPATIAL + (size_t)xx * 16384 +
               (size_t)ycol * 128 + (size_t)izg * 32;
  const float4* o4 = (const float4*)(od + odb);
  float4 ovv[8];
#pragma unroll
  for (int r = 0; r < 8; ++r) ovv[r] = o4[r];
  const float* of = (const float*)ovv;

  float dist = 0.f;
#pragma unroll
  for (int cb = 0; cb < 2; ++cb) {
    int izb = izg * 32 + cb * 16;
    float best[16], mc[16];
#pragma unroll
    for (int k = 0; k < 16; ++k) {
      best[k] = 3.0e38f;
      mc[k] = -2.0f * (float)(izb + k);
    }
    float jb = (float)(izb - 8);
#pragma unroll 4
    for (int p = 0; p < 16; ++p) {
      float h0 = hl[(izb + 2 * p) * 129 + ycol];
      float h1 = hl[(izb + 2 * p + 1) * 129 + ycol];
      float j0 = jb + (float)(2 * p), j1 = jb + (float)(2 * p + 1);
#pragma unroll
      for (int k = 0; k < 16; ++k) {
        float v0 = fmaf(mc[k], j0, h0);
        float v1 = fmaf(mc[k], j1, h1);
        best[k] = min3f(v0, v1, best[k]);
      }
    }
    float dv[16];
    int ok = 1;
#pragma unroll
    for (int k = 0; k < 16; ++k) {
      int i = izb + k;
      dv[k] = (float)(i * i) + best[k];
      float bnd = (float)min((k + 9) * (k + 9), (24 - k) * (24 - k));
      ok &= (dv[k] <= bnd);
    }
    if (!__all(ok)) {
#pragma unroll
      for (int k = 0; k < 16; ++k) best[k] = 3.0e38f;
#pragma unroll 2
      for (int j = 0; j < 128; j += 2) {
        float h0 = hl[(j + 8) * 129 + ycol];
        float h1 = hl[(j + 9) * 129 + ycol];
        float j0 = (float)j, j1 = (float)(j + 1);
#pragma unroll
        for (int k = 0; k < 16; ++k) {
          float v0 = fmaf(mc[k], j0, h0);
          float v1 = fmaf(mc[k], j1, h1);
          best[k] = min3f(v0, v1, best[k]);
        }
      }
#pragma unroll
      for (int k = 0; k < 16; ++k) {
        int i = izb + k;
        dv[k] = (float)(i * i) + best[k];
      }
    }
#pragma unroll
    for (int k = 0; k < 16; ++k) {
      if (dv[k] > 0.f) dist += fabsf(of[cb * 16 + k] - sqrtf(dv[k]));
    }
  }
  float r = wave_redf(dist);
  int lane = t & 63, w = t >> 6;
  if (lane == 0) sred[w] = r;
  __syncthreads();
  if (t == 0) {
    float s = 0.f;
#pragma unroll
    for (int q = 0; q < 8; ++q) s += sred[q];
    part[2048 + blk] = (double)s;
  }
}

// ---------------------------------------------------------------------------
// k_final: reduce partials (512 ce/dice slots, 256 dist slots) -> loss.
// ---------------------------------------------------------------------------
__global__ __launch_bounds__(256) void k_final(const double* __restrict__ part,
                                               const float* __restrict__ wptr,
                                               float* __restrict__ out) {
  int i = threadIdx.x;
  double ce  = part[i] + part[i + 256];
  double p0  = part[512 + i];
  double p1  = part[768 + i];
  double pt0 = part[1024 + i];
  double pt1 = part[1280 + i];
  double t0  = part[1536 + i];
  double t1  = part[1792 + i];
  double ds  = part[2048 + i];   // 256 kCD blocks

  ce = wave_redd(ce); p0 = wave_redd(p0); p1 = wave_redd(p1);
  pt0 = wave_redd(pt0); pt1 = wave_redd(pt1);
  t0 = wave_redd(t0); t1 = wave_redd(t1); ds = wave_redd(ds);

  __shared__ double sm[4][8];
  int lane = threadIdx.x & 63, w = threadIdx.x >> 6;
  if (lane == 0) {
    sm[w][0] = ce; sm[w][1] = p0; sm[w][2] = p1; sm[w][3] = pt0;
    sm[w][4] = pt1; sm[w][5] = t0; sm[w][6] = t1; sm[w][7] = ds;
  }
  __syncthreads();
  if (threadIdx.x == 0) {
    double a[8];
    for (int q = 0; q < 8; ++q) a[q] = sm[0][q] + sm[1][q] + sm[2][q] + sm[3][q];
    double cem = a[0] / 4194304.0;
    double dice0 = (2.0 * a[3] + 1.0) / (a[1] + a[5] + 1.0);
    double dice1 = (2.0 * a[4] + 1.0) / (a[2] + a[6] + 1.0);
    double ldice = 1.0 - 0.5 * (dice0 + dice1);
    double msum = a[5] + a[6];
    double ldist = (msum == 0.0) ? 0.0 : a[7] / fmax(msum, 1e-12);
    out[0] = (float)(cem + ldice + (double)wptr[0] * ldist);
  }
}

extern "C" void kernel_launch(void* const* d_in, const int* in_sizes, int n_in,
                              void* d_out, int out_size, void* d_ws, size_t ws_size,
                              hipStream_t stream) {
  const float* outputs      = (const float*)d_in[0];
  const float* outputs_dist = (const float*)d_in[1];
  const int*   y            = (const int*)d_in[2];
  const float* wptr         = (const float*)d_in[3];
  float* out = (float*)d_out;

  double* part = (double*)d_ws;                    // 2304 doubles
  float* gT = (float*)((char*)d_ws + 65536);       // 16 MiB transposed h field

  kAB<<<512, 256, 0, stream>>>(y, outputs, gT, part);      // X + CE/dice
  kCD<<<256, 512, 0, stream>>>(gT, outputs_dist, part);    // fused Y+Z + dist
  k_final<<<1, 256, 0, stream>>>(part, wptr, out);
}